// Round 2
// baseline (216.353 us; speedup 1.0000x reference)
//
#include <hip/hip_runtime.h>
#include <math.h>
#include <type_traits>

// Problem constants (B=2, S=2048, D=1024, H=16, hd=64)
#define B_  2
#define S_  2048
#define D_  1024
#define H_  16

typedef short bf16x8 __attribute__((ext_vector_type(8)));
typedef short bf16x4 __attribute__((ext_vector_type(4)));
typedef float f32x4  __attribute__((ext_vector_type(4)));

// fp32 -> bf16 bits, round-to-nearest-even (finite inputs only)
__device__ __forceinline__ short f2bf(float f) {
    unsigned u = __builtin_bit_cast(unsigned, f);
    u += 0x7FFFu + ((u >> 16) & 1u);
    return (short)(u >> 16);
}
__device__ __forceinline__ float bf2f(short s) {
    unsigned u = ((unsigned)(unsigned short)s) << 16;
    return __builtin_bit_cast(float, u);
}

// async global->LDS, 16B per lane; LDS dest = wave-uniform base + lane*16
__device__ __forceinline__ void gload16(const short* g, const void* l) {
    __builtin_amdgcn_global_load_lds(
        (const __attribute__((address_space(1))) void*)g,
        (__attribute__((address_space(3))) void*)l, 16, 0, 0);
}

// ---------------------------------------------------------------------------
// fp32 -> bf16 elementwise (8 elems/thread)
// ---------------------------------------------------------------------------
__global__ __launch_bounds__(256) void cvt_bf16_kernel(
    const float* __restrict__ in, short* __restrict__ out)
{
    int i = (blockIdx.x * 256 + threadIdx.x) * 8;
    float4 a = *(const float4*)(in + i);
    float4 b = *(const float4*)(in + i + 4);
    bf16x8 o;
    o[0] = f2bf(a.x); o[1] = f2bf(a.y); o[2] = f2bf(a.z); o[3] = f2bf(a.w);
    o[4] = f2bf(b.x); o[5] = f2bf(b.y); o[6] = f2bf(b.z); o[7] = f2bf(b.w);
    *(bf16x8*)(out + i) = o;
}

// ---------------------------------------------------------------------------
// fp32 [K][N] -> bf16 [N][K] transpose via LDS. Grid (N/64, K/64).
// ---------------------------------------------------------------------------
__global__ __launch_bounds__(256) void transpose_cvt_kernel(
    const float* __restrict__ in, short* __restrict__ out, int K, int N)
{
    __shared__ short t[64][72];
    const int k0 = blockIdx.y * 64, n0 = blockIdx.x * 64;
    const int r = threadIdx.x >> 2;
    const int c = (threadIdx.x & 3) * 16;
    const float* src = in + (size_t)(k0 + r) * N + n0 + c;
#pragma unroll
    for (int i = 0; i < 16; ++i) t[c + i][r] = f2bf(src[i]);
    __syncthreads();
    short* dst = out + (size_t)(n0 + r) * K + k0 + c;
    *(bf16x8*)(dst)     = *(const bf16x8*)&t[r][c];
    *(bf16x8*)(dst + 8) = *(const bf16x8*)&t[r][c + 8];
}

// ---------------------------------------------------------------------------
// RoPE cos/sin table: tab[s*32+j] = (cos, sin) of s / 10000^(j/32)
// ---------------------------------------------------------------------------
__global__ __launch_bounds__(256) void rope_tab_kernel(float2* __restrict__ tab)
{
    int idx = blockIdx.x * 256 + threadIdx.x;   // < 2048*32
    int j = idx & 31, s = idx >> 5;
    float inv = powf(10000.0f, -(float)j * (1.0f / 32.0f));
    float sn, cs;
    sincosf((float)s * inv, &sn, &cs);
    tab[idx] = make_float2(cs, sn);
}

// ---------------------------------------------------------------------------
// bf16 MFMA GEMM, 128x64 tile (M x N), BK=32, fp32 out. 256 thr = 4 waves
// (2x2). Triple-buffered LDS ring, prefetch distance 2, counted vmcnt(3),
// one raw s_barrier per K-step.
// ---------------------------------------------------------------------------
__global__ __launch_bounds__(256) void gemm_bt_f32(
    const short* __restrict__ A, const short* __restrict__ Bt,
    float* __restrict__ C, int M, int N, int K)
{
    __shared__ short smem[18432];   // 3 x (As 8KB | Bs 4KB) = 36864 B

    const int tid  = threadIdx.x;
    const int wave = tid >> 6, lane = tid & 63;
    const int quad = lane >> 4, l16 = lane & 15;
    const int wm = wave >> 1, wn = wave & 1;
    const int row0 = blockIdx.y * 128, col0 = blockIdx.x * 64;

    f32x4 acc[4][2];
#pragma unroll
    for (int mi = 0; mi < 4; ++mi)
#pragma unroll
        for (int ni = 0; ni < 2; ++ni) acc[mi][ni] = (f32x4)0.f;

    const int sr = tid >> 2;
    const int sc = (tid & 3) * 8;
    const short* a0 = A  + (size_t)(row0 + sr) * K + sc;
    const short* a1 = A  + (size_t)(row0 + 64 + sr) * K + sc;
    const short* b0 = Bt + (size_t)(col0 + sr) * K + sc;

    auto stage = [&](int b, int kt) {
        char* l = (char*)(smem + b * 6144) + wave * 1024;
        const int k0 = kt * 32;
        gload16(a0 + k0, l);            // A rows 0-63
        gload16(a1 + k0, l + 4096);     // A rows 64-127
        gload16(b0 + k0, l + 8192);     // B rows 0-63
    };

    const int NT = K >> 5;              // 32
    stage(0, 0);
    stage(1, 1);
    int bufid = 0;
    for (int kt = 0; kt < NT; ++kt) {
        if (kt + 1 < NT) { asm volatile("s_waitcnt vmcnt(3)" ::: "memory"); }
        else             { asm volatile("s_waitcnt vmcnt(0)" ::: "memory"); }
        __builtin_amdgcn_s_barrier();
        __builtin_amdgcn_sched_barrier(0);
        if (kt + 2 < NT) {
            int nb = bufid + 2; if (nb >= 3) nb -= 3;
            stage(nb, kt + 2);          // issue-early: 2 steps ahead
        }

        const short* As = smem + bufid * 6144;
        const short* Bs = As + 4096;
        bf16x8 af[4], bfr[2];
#pragma unroll
        for (int mi = 0; mi < 4; ++mi)
            af[mi] = *(const bf16x8*)(As + (wm * 64 + mi * 16 + l16) * 32 + quad * 8);
#pragma unroll
        for (int ni = 0; ni < 2; ++ni)
            bfr[ni] = *(const bf16x8*)(Bs + (wn * 32 + ni * 16 + l16) * 32 + quad * 8);
#pragma unroll
        for (int mi = 0; mi < 4; ++mi)
#pragma unroll
            for (int ni = 0; ni < 2; ++ni)
                acc[mi][ni] = __builtin_amdgcn_mfma_f32_16x16x32_bf16(
                    af[mi], bfr[ni], acc[mi][ni], 0, 0, 0);

        bufid = (bufid + 1 == 3) ? 0 : bufid + 1;
    }

#pragma unroll
    for (int mi = 0; mi < 4; ++mi)
#pragma unroll
        for (int ni = 0; ni < 2; ++ni)
#pragma unroll
            for (int r = 0; r < 4; ++r) {
                int row = row0 + wm * 64 + mi * 16 + quad * 4 + r;
                int col = col0 + wn * 32 + ni * 16 + l16;
                C[(size_t)row * N + col] = acc[mi][ni][r];
            }
}

// ---------------------------------------------------------------------------
// Fused QKV GEMM (128x128, BK=32) with RoPE + head-major repack + V
// transpose in an LDS-STAGED epilogue. Ring-3 K-loop (3 x 16KB), prefetch
// distance 2, counted vmcnt(4), one raw s_barrier per step. Dynamic LDS
// 49152 B (3 blocks/CU).
// R12: Kb is now UNPADDED stride-64 (same layout as Qb) — attn reads K
// direct from L2, no LDS staging, so the 72-pad is dead. Q/K write paths
// merged.
// M=4096, N=3072, K=1024. grid (24, 32), 768 blocks = 3/CU exactly.
// ---------------------------------------------------------------------------
__global__ __launch_bounds__(256) void gemm_qkv(
    const short* __restrict__ A, const short* __restrict__ Bt,
    const float2* __restrict__ tab,
    short* __restrict__ Qb, short* __restrict__ Kb, short* __restrict__ Vt)
{
    const int K = 1024;
    extern __shared__ short smem[];          // 49152 B = 3 x (As 8KB | Bs 8KB)
    short* Sc = smem;                        // epilogue: 4 x (64*72)

    const int tid  = threadIdx.x;
    const int wave = tid >> 6, lane = tid & 63;
    const int quad = lane >> 4, l16 = lane & 15;
    const int wm = wave >> 1, wn = wave & 1;
    const int row0 = blockIdx.y * 128, col0 = blockIdx.x * 128;

    f32x4 acc[4][4];
#pragma unroll
    for (int mi = 0; mi < 4; ++mi)
#pragma unroll
        for (int ni = 0; ni < 4; ++ni) acc[mi][ni] = (f32x4)0.f;

    const int sr = tid >> 2;
    const int sc = (tid & 3) * 8;
    const short* a0 = A  + (size_t)(row0 + sr) * K + sc;
    const short* a1 = A  + (size_t)(row0 + 64 + sr) * K + sc;
    const short* b0 = Bt + (size_t)(col0 + sr) * K + sc;
    const short* b1 = Bt + (size_t)(col0 + 64 + sr) * K + sc;

    auto stage = [&](int b, int kt) {
        char* l = (char*)(smem + b * 8192) + wave * 1024;
        const int k0 = kt * 32;
        gload16(a0 + k0, l);            // A rows 0-63
        gload16(a1 + k0, l + 4096);     // A rows 64-127
        gload16(b0 + k0, l + 8192);     // B rows 0-63
        gload16(b1 + k0, l + 12288);    // B rows 64-127
    };

    const int NT = K >> 5;              // 32
    stage(0, 0);
    stage(1, 1);
    int bufid = 0;
    for (int kt = 0; kt < NT; ++kt) {
        if (kt + 1 < NT) { asm volatile("s_waitcnt vmcnt(4)" ::: "memory"); }
        else             { asm volatile("s_waitcnt vmcnt(0)" ::: "memory"); }
        __builtin_amdgcn_s_barrier();       // all waves' tile-kt data visible
        __builtin_amdgcn_sched_barrier(0);  // pin ds_reads/stage below barrier
        if (kt + 2 < NT) {
            int nb = bufid + 2; if (nb >= 3) nb -= 3;
            stage(nb, kt + 2);
        }

        const short* As = smem + bufid * 8192;
        const short* Bs = As + 4096;
        bf16x8 af[4], bfr[4];
#pragma unroll
        for (int mi = 0; mi < 4; ++mi)
            af[mi] = *(const bf16x8*)(As + (wm * 64 + mi * 16 + l16) * 32 + quad * 8);
#pragma unroll
        for (int ni = 0; ni < 4; ++ni)
            bfr[ni] = *(const bf16x8*)(Bs + (wn * 64 + ni * 16 + l16) * 32 + quad * 8);
#pragma unroll
        for (int mi = 0; mi < 4; ++mi)
#pragma unroll
            for (int ni = 0; ni < 4; ++ni)
                acc[mi][ni] = __builtin_amdgcn_mfma_f32_16x16x32_bf16(
                    af[mi], bfr[ni], acc[mi][ni], 0, 0, 0);

        bufid = (bufid + 1 == 3) ? 0 : bufid + 1;
    }

    __syncthreads();   // full drain; Sc may now overwrite the ring buffers

    const int sec  = (col0 + wn * 64) >> 6;   // 0..47
    const int h    = sec & 15;
    const int kind = sec >> 4;                // 0=Q, 1=K, 2=V
    short* myS = Sc + wave * 4608;            // 64 x 72 scratch

    const int mrow0 = row0 + wm * 64;         // block never straddles b
    const int b  = mrow0 >> 11;
    const int bh = b * 16 + h;
    const int sbase = mrow0 & (S_ - 1);

    if (kind < 2) {
        // ---- Q/K: RoPE -> scratch [s][d] ----
#pragma unroll
        for (int mi = 0; mi < 4; ++mi) {
#pragma unroll
            for (int r = 0; r < 4; ++r) {
                int sl = mi * 16 + quad * 4 + r;
                int s = sbase + sl;
#pragma unroll
                for (int ni = 0; ni < 2; ++ni) {
                    int j = ni * 16 + l16;
                    float2 t = tab[s * 32 + j];
                    float lo = acc[mi][ni][r], hi = acc[mi][ni + 2][r];
                    float olo = lo * t.x - hi * t.y;
                    float ohi = hi * t.x + lo * t.y;
                    if (kind == 0) { olo *= 0.125f; ohi *= 0.125f; }
                    myS[sl * 72 + j]      = f2bf(olo);
                    myS[sl * 72 + 32 + j] = f2bf(ohi);
                }
            }
        }
        // readout: 8 lanes x 16B cover one 128B row (wave-private, no barrier)
        const int rl = lane >> 3;             // row sub-index
        const int cl = (lane & 7) * 8;        // col in shorts
        short* dst = (kind == 0 ? Qb : Kb);
#pragma unroll
        for (int p = 0; p < 8; ++p) {
            int rr = p * 8 + rl;
            bf16x8 v = *(const bf16x8*)&myS[rr * 72 + cl];
            *(bf16x8*)(dst + ((size_t)bh * S_ + sbase + rr) * 64 + cl) = v;
        }
    } else {
        // ---- V: scratch [d][s], r=0..3 packed as b64 ----
#pragma unroll
        for (int mi = 0; mi < 4; ++mi)
#pragma unroll
            for (int ni = 0; ni < 4; ++ni) {
                bf16x4 p;
                p[0] = f2bf(acc[mi][ni][0]);
                p[1] = f2bf(acc[mi][ni][1]);
                p[2] = f2bf(acc[mi][ni][2]);
                p[3] = f2bf(acc[mi][ni][3]);
                *(bf16x4*)&myS[(ni * 16 + l16) * 72 + mi * 16 + quad * 4] = p;
            }
        const int rl = lane >> 3;
        const int cl = (lane & 7) * 8;
#pragma unroll
        for (int p = 0; p < 8; ++p) {
            int dd = p * 8 + rl;
            bf16x8 v = *(const bf16x8*)&myS[dd * 72 + cl];
            *(bf16x8*)(Vt + ((size_t)bh * 64 + dd) * S_ + sbase + cl) = v;
        }
    }
}

// ---------------------------------------------------------------------------
// MFMA flash attention, R12: BARRIER-FREE, no K/V LDS staging.
// Rationale: per-head K+V = 512KB; XCD swizzle keeps 4 heads (2MB) resident
// in one XCD's 4MB L2 -> staging L2-fit data in LDS was pure overhead
// (lockstep __syncthreads + vmcnt(0) drains + staging VALU).
// Structure: 128 thr = 2 waves, each wave owns 32 q-rows (2 chunks of 16).
//  - K/V tiles shared per block only through L1/L2 (2 waves -> 2x L2 reads,
//    ~540MB total ≈ 15us at L2 BW).
//  - Swapped QK^T: s4 = mfma(Kfrag, Qfrag) = S^T; lane holds 4 k-contig P
//    values per (chunk,nt) -> P spill is 4 packed ds_write_b64 per chunk
//    (was 16 conflicted ds_write_b16).
//  - Ps slices wave-private -> ZERO barriers in the kernel.
// Shifted-exp softmax (p = exp(s-8)); l row-sums via MFMA with ones frag.
// Same split-K task map: 2560 blocks; lin%8 = XCD, bh = xcd*4 + (lin/8)%4.
// ---------------------------------------------------------------------------
__global__ __launch_bounds__(128, 4) void attn_kernel(
    const short* __restrict__ Qb, const short* __restrict__ Kb,
    const short* __restrict__ Vt, short* __restrict__ Opart,
    float* __restrict__ lpart)
{
    __shared__ short Ps[64][72];     // 9216 B; rows wave*32+m*16+l16

    const int lin = blockIdx.x;
    const int xcd = lin & 7;
    const int j   = lin >> 3;            // 0..319
    const int bh   = xcd * 4 + (j & 3);
    const int task = j >> 2;             // 0..79

    const int g = task < 8 ? 0 : task < 24 ? 1 : task < 48 ? 2 : 3;
    const int cumstart = g == 0 ? 0 : g == 1 ? 8 : g == 2 ? 24 : 48;
    const int idx = task - cumstart;
    const int qd = idx / (g + 1);
    const int qb = 8 * g + qd;
    const int c  = idx - qd * (g + 1);
    const int t0 = c * 8;
    const int t1 = min(qb, c * 8 + 7);

    const int wave = threadIdx.x >> 6, lane = threadIdx.x & 63;
    const int quad = lane >> 4, l16 = lane & 15;
    const size_t head64 = (size_t)bh * S_ * 64;   // Qb / Kb / Vt element base

    // Q B-frags (col=q=l16, rows d=quad*8..) straight from global; 2 chunks
    bf16x8 qf[2][2];
#pragma unroll
    for (int m = 0; m < 2; ++m) {
        const short* qrow = Qb + head64
            + (size_t)(qb * 64 + wave * 32 + m * 16 + l16) * 64 + quad * 8;
        qf[m][0] = *(const bf16x8*)(qrow);
        qf[m][1] = *(const bf16x8*)(qrow + 32);
    }

    // all-ones bf16 B fragment for l row-sums
    bf16x8 ones;
#pragma unroll
    for (int i = 0; i < 8; ++i) ones[i] = (short)0x3F80;

    f32x4 lacc[2] = {(f32x4)0.f, (f32x4)0.f};
    f32x4 oacc[2][4];
#pragma unroll
    for (int m = 0; m < 2; ++m)
#pragma unroll
        for (int nt = 0; nt < 4; ++nt) oacc[m][nt] = (f32x4)0.f;

    for (int t = t0; t <= t1; ++t) {
        const short* kb = Kb + head64 + (size_t)t * 64 * 64;  // [64 s][64 d]
        const short* vb = Vt + head64 + t * 64;               // [64 d][2048 s]

        // ---- QK^T (swapped): s4[m][nt] = S^T, row k=quad*4+r, col q=l16 ----
        f32x4 s4[2][4];
#pragma unroll
        for (int nt = 0; nt < 4; ++nt) {
            const short* kr = kb + (nt * 16 + l16) * 64 + quad * 8;
            bf16x8 k0 = *(const bf16x8*)kr;
            bf16x8 k1 = *(const bf16x8*)(kr + 32);
#pragma unroll
            for (int m = 0; m < 2; ++m) {
                f32x4 a = (f32x4)0.f;
                a = __builtin_amdgcn_mfma_f32_16x16x32_bf16(k0, qf[m][0], a, 0, 0, 0);
                a = __builtin_amdgcn_mfma_f32_16x16x32_bf16(k1, qf[m][1], a, 0, 0, 0);
                s4[m][nt] = a;
            }
        }

        // causal mask: only the diagonal tile (k_local > q_local)
        if (t == qb) {
#pragma unroll
            for (int m = 0; m < 2; ++m)
#pragma unroll
                for (int nt = 0; nt < 4; ++nt)
#pragma unroll
                    for (int r = 0; r < 4; ++r)
                        if (nt * 16 + quad * 4 + r > wave * 32 + m * 16 + l16)
                            s4[m][nt][r] = -INFINITY;
        }

        // ---- p = exp(s - 8) -> packed b64 writes (k-contig per lane) ----
#pragma unroll
        for (int m = 0; m < 2; ++m)
#pragma unroll
            for (int nt = 0; nt < 4; ++nt) {
                bf16x4 p;
#pragma unroll
                for (int r = 0; r < 4; ++r)
                    p[r] = f2bf(__expf(s4[m][nt][r] - 8.0f));  // masked -> 0
                *(bf16x4*)&Ps[wave * 32 + m * 16 + l16][nt * 16 + quad * 4] = p;
            }

        // ---- read P A-frags (row q=l16, k-contig) ----
        bf16x8 pa[2][2];
#pragma unroll
        for (int m = 0; m < 2; ++m) {
            pa[m][0] = *(const bf16x8*)&Ps[wave * 32 + m * 16 + l16][quad * 8];
            pa[m][1] = *(const bf16x8*)&Ps[wave * 32 + m * 16 + l16][32 + quad * 8];
        }

        // ---- l row-sum (MFMA with ones) ----
#pragma unroll
        for (int m = 0; m < 2; ++m) {
            lacc[m] = __builtin_amdgcn_mfma_f32_16x16x32_bf16(pa[m][0], ones, lacc[m], 0, 0, 0);
            lacc[m] = __builtin_amdgcn_mfma_f32_16x16x32_bf16(pa[m][1], ones, lacc[m], 0, 0, 0);
        }

        // ---- PV: V B-frags direct from L2, shared across both chunks ----
#pragma unroll
        for (int nt = 0; nt < 4; ++nt) {
            const short* vrp = vb + (size_t)(nt * 16 + l16) * S_ + quad * 8;
            bf16x8 vb0 = *(const bf16x8*)vrp;
            bf16x8 vb1 = *(const bf16x8*)(vrp + 32);
#pragma unroll
            for (int m = 0; m < 2; ++m) {
                oacc[m][nt] = __builtin_amdgcn_mfma_f32_16x16x32_bf16(
                    pa[m][0], vb0, oacc[m][nt], 0, 0, 0);
                oacc[m][nt] = __builtin_amdgcn_mfma_f32_16x16x32_bf16(
                    pa[m][1], vb1, oacc[m][nt], 0, 0, 0);
            }
        }
    }

    // ---- epilogue: unnormalized partial O (bf16) + l (f32) ----
    const int pidx = bh * 80 + task;
#pragma unroll
    for (int m = 0; m < 2; ++m)
#pragma unroll
        for (int r = 0; r < 4; ++r) {
            int ql = wave * 32 + m * 16 + quad * 4 + r;
            short* orow = Opart + (size_t)pidx * 4096 + ql * 64;
#pragma unroll
            for (int nt = 0; nt < 4; ++nt)
                orow[nt * 16 + l16] = f2bf(oacc[m][nt][r]);
            if (l16 == 0)
                lpart[(size_t)pidx * 64 + ql] = lacc[m][r];
        }
}

// ---------------------------------------------------------------------------
// Combine split-K partials: attnb = (sum_c O_c) / (sum_c l_c)
// grid (32 qb, 32 bh), 256 thr: thread = (q = tid>>2, 16-d group).
// ---------------------------------------------------------------------------
__global__ __launch_bounds__(256) void combine_kernel(
    const short* __restrict__ Opart, const float* __restrict__ lpart,
    short* __restrict__ attnb)
{
    const int qb = blockIdx.x, bh = blockIdx.y;
    const int g = qb >> 3, nch = g + 1;
    const int cbase = bh * 80 + nch * (qb - 4 * g);
    const int q = threadIdx.x >> 2;
    const int dg = (threadIdx.x & 3) * 16;

    float lsum = 0.f;
    float acc[16];
#pragma unroll
    for (int i = 0; i < 16; ++i) acc[i] = 0.f;

    for (int cc = 0; cc < nch; ++cc) {
        lsum += lpart[(size_t)(cbase + cc) * 64 + q];
        const short* src = Opart + (size_t)(cbase + cc) * 4096 + q * 64 + dg;
        bf16x8 o0 = *(const bf16x8*)src;
        bf16x8 o1 = *(const bf16x8*)(src + 8);
#pragma unroll
        for (int i = 0; i < 8; ++i) {
            acc[i]     += bf2f(o0[i]);
            acc[i + 8] += bf2f(o1[i]);
        }
    }
    float inv = 1.0f / lsum;
    const int b = bh >> 4, h = bh & 15;
    bf16x8 r0, r1;
#pragma unroll
    for (int i = 0; i < 8; ++i) {
        r0[i] = f2bf(acc[i] * inv);
        r1[i] = f2bf(acc[i + 8] * inv);
    }
    short* dst = attnb + (size_t)(b * S_ + qb * 64 + q) * 1024 + h * 64 + dg;
    *(bf16x8*)dst       = r0;
    *(bf16x8*)(dst + 8) = r1;
}

// ---------------------------------------------------------------------------
extern "C" void kernel_launch(void* const* d_in, const int* in_sizes, int n_in,
                              void* d_out, int out_size, void* d_ws, size_t ws_size,
                              hipStream_t stream)
{
    const float* x     = (const float*)d_in[0];   // [2,2048,1024]
    const float* w_qkv = (const float*)d_in[1];   // [1024,3072]
    const float* w_out = (const float*)d_in[2];   // [1024,1024]
    float* out = (float*)d_out;                   // [2,2048,1024]

    // workspace layout (bf16 shorts unless noted), ~64 MB total
    short* Qb   = (short*)d_ws;                        // [32][2048][64] 8.4 MB
    short* Kb   = Qb   + (size_t)4096 * 1024;          // [32][2048][64] 8.4 MB
    short* Vt   = Kb   + (size_t)4096 * 1024;          // [32][64][2048] 8.4 MB
    short* Xb   = Vt   + (size_t)4096 * 1024;          // [4096][1024]   8.4 MB
    short* Wqt  = Xb   + (size_t)4096 * 1024;          // [3072][1024]   6.3 MB
    short* Wot  = Wqt  + (size_t)3072 * 1024;          // [1024][1024]   2.1 MB
    float2* tab = (float2*)(Wot + (size_t)1024 * 1024); // [2048*32]     0.5 MB
    short* Opart = (short*)(tab + 2048 * 32);          // 2560*4096     21.0 MB
    float* lbuf  = (float*)(Opart + (size_t)2560 * 4096); // 2560*64     0.65 MB
    short* attnb = Xb;   // Xb dead after gemm_qkv; reuse for attention output

    // 1) conversions / transposes / RoPE table
    cvt_bf16_kernel<<<(4096 * 1024 / 8) / 256, 256, 0, stream>>>(x, Xb);
    transpose_cvt_kernel<<<dim3(3072 / 64, 1024 / 64), 256, 0, stream>>>(
        w_qkv, Wqt, 1024, 3072);
    transpose_cvt_kernel<<<dim3(1024 / 64, 1024 / 64), 256, 0, stream>>>(
        w_out, Wot, 1024, 1024);
    rope_tab_kernel<<<(2048 * 32) / 256, 256, 0, stream>>>(tab);

    // 2) fused QKV GEMM (ring-3 pipelined K-loop): Xb @ Wqt^T -> Qb/Kb/Vt
    gemm_qkv<<<dim3(3072 / 128, 4096 / 128), 256, 49152, stream>>>(
        Xb, Wqt, tab, Qb, Kb, Vt);

    // 3) barrier-free split-K flash attention -> partials
    attn_kernel<<<2560, 128, 0, stream>>>(Qb, Kb, Vt, Opart, lbuf);

    // 4) combine partials -> attnb bf16 [4096][1024]
    combine_kernel<<<dim3(32, 32), 256, 0, stream>>>(Opart, lbuf, attnb);

    // 5) out = attnb @ Wot^T  (fp32 out, ring-3 pipelined, 512 blocks)
    gemm_bt_f32<<<dim3(1024 / 64, 4096 / 128), 256, 0, stream>>>(
        attnb, Wot, out, 4096, 1024, 1024);
}

// Round 3
// 178.495 us; speedup vs baseline: 1.2121x; 1.2121x over previous
//
#include <hip/hip_runtime.h>
#include <math.h>
#include <type_traits>

// Problem constants (B=2, S=2048, D=1024, H=16, hd=64)
#define B_  2
#define S_  2048
#define D_  1024
#define H_  16

typedef short bf16x8 __attribute__((ext_vector_type(8)));
typedef short bf16x4 __attribute__((ext_vector_type(4)));
typedef float f32x4  __attribute__((ext_vector_type(4)));

// fp32 -> bf16 bits, round-to-nearest-even (finite inputs only)
__device__ __forceinline__ short f2bf(float f) {
    unsigned u = __builtin_bit_cast(unsigned, f);
    u += 0x7FFFu + ((u >> 16) & 1u);
    return (short)(u >> 16);
}
__device__ __forceinline__ float bf2f(short s) {
    unsigned u = ((unsigned)(unsigned short)s) << 16;
    return __builtin_bit_cast(float, u);
}

// async global->LDS, 16B per lane; LDS dest = wave-uniform base + lane*16
__device__ __forceinline__ void gload16(const short* g, const void* l) {
    __builtin_amdgcn_global_load_lds(
        (const __attribute__((address_space(1))) void*)g,
        (__attribute__((address_space(3))) void*)l, 16, 0, 0);
}

// ---------------------------------------------------------------------------
// fp32 -> bf16 elementwise (8 elems/thread)
// ---------------------------------------------------------------------------
__global__ __launch_bounds__(256) void cvt_bf16_kernel(
    const float* __restrict__ in, short* __restrict__ out)
{
    int i = (blockIdx.x * 256 + threadIdx.x) * 8;
    float4 a = *(const float4*)(in + i);
    float4 b = *(const float4*)(in + i + 4);
    bf16x8 o;
    o[0] = f2bf(a.x); o[1] = f2bf(a.y); o[2] = f2bf(a.z); o[3] = f2bf(a.w);
    o[4] = f2bf(b.x); o[5] = f2bf(b.y); o[6] = f2bf(b.z); o[7] = f2bf(b.w);
    *(bf16x8*)(out + i) = o;
}

// ---------------------------------------------------------------------------
// fp32 [K][N] -> bf16 [N][K] transpose via LDS. Grid (N/64, K/64).
// ---------------------------------------------------------------------------
__global__ __launch_bounds__(256) void transpose_cvt_kernel(
    const float* __restrict__ in, short* __restrict__ out, int K, int N)
{
    __shared__ short t[64][72];
    const int k0 = blockIdx.y * 64, n0 = blockIdx.x * 64;
    const int r = threadIdx.x >> 2;
    const int c = (threadIdx.x & 3) * 16;
    const float* src = in + (size_t)(k0 + r) * N + n0 + c;
#pragma unroll
    for (int i = 0; i < 16; ++i) t[c + i][r] = f2bf(src[i]);
    __syncthreads();
    short* dst = out + (size_t)(n0 + r) * K + k0 + c;
    *(bf16x8*)(dst)     = *(const bf16x8*)&t[r][c];
    *(bf16x8*)(dst + 8) = *(const bf16x8*)&t[r][c + 8];
}

// ---------------------------------------------------------------------------
// RoPE cos/sin table: tab[s*32+j] = (cos, sin) of s / 10000^(j/32)
// ---------------------------------------------------------------------------
__global__ __launch_bounds__(256) void rope_tab_kernel(float2* __restrict__ tab)
{
    int idx = blockIdx.x * 256 + threadIdx.x;   // < 2048*32
    int j = idx & 31, s = idx >> 5;
    float inv = powf(10000.0f, -(float)j * (1.0f / 32.0f));
    float sn, cs;
    sincosf((float)s * inv, &sn, &cs);
    tab[idx] = make_float2(cs, sn);
}

// ---------------------------------------------------------------------------
// bf16 MFMA GEMM, 128x64 tile (M x N), BK=32, fp32 out. 256 thr = 4 waves
// (2x2). Triple-buffered LDS ring, prefetch distance 2, counted vmcnt(3),
// one raw s_barrier per K-step.
// ---------------------------------------------------------------------------
__global__ __launch_bounds__(256) void gemm_bt_f32(
    const short* __restrict__ A, const short* __restrict__ Bt,
    float* __restrict__ C, int M, int N, int K)
{
    __shared__ short smem[18432];   // 3 x (As 8KB | Bs 4KB) = 36864 B

    const int tid  = threadIdx.x;
    const int wave = tid >> 6, lane = tid & 63;
    const int quad = lane >> 4, l16 = lane & 15;
    const int wm = wave >> 1, wn = wave & 1;
    const int row0 = blockIdx.y * 128, col0 = blockIdx.x * 64;

    f32x4 acc[4][2];
#pragma unroll
    for (int mi = 0; mi < 4; ++mi)
#pragma unroll
        for (int ni = 0; ni < 2; ++ni) acc[mi][ni] = (f32x4)0.f;

    const int sr = tid >> 2;
    const int sc = (tid & 3) * 8;
    const short* a0 = A  + (size_t)(row0 + sr) * K + sc;
    const short* a1 = A  + (size_t)(row0 + 64 + sr) * K + sc;
    const short* b0 = Bt + (size_t)(col0 + sr) * K + sc;

    auto stage = [&](int b, int kt) {
        char* l = (char*)(smem + b * 6144) + wave * 1024;
        const int k0 = kt * 32;
        gload16(a0 + k0, l);            // A rows 0-63
        gload16(a1 + k0, l + 4096);     // A rows 64-127
        gload16(b0 + k0, l + 8192);     // B rows 0-63
    };

    const int NT = K >> 5;              // 32
    stage(0, 0);
    stage(1, 1);
    int bufid = 0;
    for (int kt = 0; kt < NT; ++kt) {
        if (kt + 1 < NT) { asm volatile("s_waitcnt vmcnt(3)" ::: "memory"); }
        else             { asm volatile("s_waitcnt vmcnt(0)" ::: "memory"); }
        __builtin_amdgcn_s_barrier();
        __builtin_amdgcn_sched_barrier(0);
        if (kt + 2 < NT) {
            int nb = bufid + 2; if (nb >= 3) nb -= 3;
            stage(nb, kt + 2);          // issue-early: 2 steps ahead
        }

        const short* As = smem + bufid * 6144;
        const short* Bs = As + 4096;
        bf16x8 af[4], bfr[2];
#pragma unroll
        for (int mi = 0; mi < 4; ++mi)
            af[mi] = *(const bf16x8*)(As + (wm * 64 + mi * 16 + l16) * 32 + quad * 8);
#pragma unroll
        for (int ni = 0; ni < 2; ++ni)
            bfr[ni] = *(const bf16x8*)(Bs + (wn * 32 + ni * 16 + l16) * 32 + quad * 8);
#pragma unroll
        for (int mi = 0; mi < 4; ++mi)
#pragma unroll
            for (int ni = 0; ni < 2; ++ni)
                acc[mi][ni] = __builtin_amdgcn_mfma_f32_16x16x32_bf16(
                    af[mi], bfr[ni], acc[mi][ni], 0, 0, 0);

        bufid = (bufid + 1 == 3) ? 0 : bufid + 1;
    }

#pragma unroll
    for (int mi = 0; mi < 4; ++mi)
#pragma unroll
        for (int ni = 0; ni < 2; ++ni)
#pragma unroll
            for (int r = 0; r < 4; ++r) {
                int row = row0 + wm * 64 + mi * 16 + quad * 4 + r;
                int col = col0 + wn * 32 + ni * 16 + l16;
                C[(size_t)row * N + col] = acc[mi][ni][r];
            }
}

// ---------------------------------------------------------------------------
// Fused QKV GEMM (128x128, BK=32) with RoPE + head-major repack + V
// transpose in an LDS-STAGED epilogue. Ring-3 K-loop (3 x 16KB), prefetch
// distance 2, counted vmcnt(4), one raw s_barrier per step. Dynamic LDS
// 49152 B (3 blocks/CU). Kb unpadded stride-64 (Q/K paths merged).
// M=4096, N=3072, K=1024. grid (24, 32), 768 blocks = 3/CU exactly.
// ---------------------------------------------------------------------------
__global__ __launch_bounds__(256) void gemm_qkv(
    const short* __restrict__ A, const short* __restrict__ Bt,
    const float2* __restrict__ tab,
    short* __restrict__ Qb, short* __restrict__ Kb, short* __restrict__ Vt)
{
    const int K = 1024;
    extern __shared__ short smem[];          // 49152 B = 3 x (As 8KB | Bs 8KB)
    short* Sc = smem;                        // epilogue: 4 x (64*72)

    const int tid  = threadIdx.x;
    const int wave = tid >> 6, lane = tid & 63;
    const int quad = lane >> 4, l16 = lane & 15;
    const int wm = wave >> 1, wn = wave & 1;
    const int row0 = blockIdx.y * 128, col0 = blockIdx.x * 128;

    f32x4 acc[4][4];
#pragma unroll
    for (int mi = 0; mi < 4; ++mi)
#pragma unroll
        for (int ni = 0; ni < 4; ++ni) acc[mi][ni] = (f32x4)0.f;

    const int sr = tid >> 2;
    const int sc = (tid & 3) * 8;
    const short* a0 = A  + (size_t)(row0 + sr) * K + sc;
    const short* a1 = A  + (size_t)(row0 + 64 + sr) * K + sc;
    const short* b0 = Bt + (size_t)(col0 + sr) * K + sc;
    const short* b1 = Bt + (size_t)(col0 + 64 + sr) * K + sc;

    auto stage = [&](int b, int kt) {
        char* l = (char*)(smem + b * 8192) + wave * 1024;
        const int k0 = kt * 32;
        gload16(a0 + k0, l);            // A rows 0-63
        gload16(a1 + k0, l + 4096);     // A rows 64-127
        gload16(b0 + k0, l + 8192);     // B rows 0-63
        gload16(b1 + k0, l + 12288);    // B rows 64-127
    };

    const int NT = K >> 5;              // 32
    stage(0, 0);
    stage(1, 1);
    int bufid = 0;
    for (int kt = 0; kt < NT; ++kt) {
        if (kt + 1 < NT) { asm volatile("s_waitcnt vmcnt(4)" ::: "memory"); }
        else             { asm volatile("s_waitcnt vmcnt(0)" ::: "memory"); }
        __builtin_amdgcn_s_barrier();       // all waves' tile-kt data visible
        __builtin_amdgcn_sched_barrier(0);  // pin ds_reads/stage below barrier
        if (kt + 2 < NT) {
            int nb = bufid + 2; if (nb >= 3) nb -= 3;
            stage(nb, kt + 2);
        }

        const short* As = smem + bufid * 8192;
        const short* Bs = As + 4096;
        bf16x8 af[4], bfr[4];
#pragma unroll
        for (int mi = 0; mi < 4; ++mi)
            af[mi] = *(const bf16x8*)(As + (wm * 64 + mi * 16 + l16) * 32 + quad * 8);
#pragma unroll
        for (int ni = 0; ni < 4; ++ni)
            bfr[ni] = *(const bf16x8*)(Bs + (wn * 64 + ni * 16 + l16) * 32 + quad * 8);
#pragma unroll
        for (int mi = 0; mi < 4; ++mi)
#pragma unroll
            for (int ni = 0; ni < 4; ++ni)
                acc[mi][ni] = __builtin_amdgcn_mfma_f32_16x16x32_bf16(
                    af[mi], bfr[ni], acc[mi][ni], 0, 0, 0);

        bufid = (bufid + 1 == 3) ? 0 : bufid + 1;
    }

    __syncthreads();   // full drain; Sc may now overwrite the ring buffers

    const int sec  = (col0 + wn * 64) >> 6;   // 0..47
    const int h    = sec & 15;
    const int kind = sec >> 4;                // 0=Q, 1=K, 2=V
    short* myS = Sc + wave * 4608;            // 64 x 72 scratch

    const int mrow0 = row0 + wm * 64;         // block never straddles b
    const int b  = mrow0 >> 11;
    const int bh = b * 16 + h;
    const int sbase = mrow0 & (S_ - 1);

    if (kind < 2) {
        // ---- Q/K: RoPE -> scratch [s][d] ----
#pragma unroll
        for (int mi = 0; mi < 4; ++mi) {
#pragma unroll
            for (int r = 0; r < 4; ++r) {
                int sl = mi * 16 + quad * 4 + r;
                int s = sbase + sl;
#pragma unroll
                for (int ni = 0; ni < 2; ++ni) {
                    int j = ni * 16 + l16;
                    float2 t = tab[s * 32 + j];
                    float lo = acc[mi][ni][r], hi = acc[mi][ni + 2][r];
                    float olo = lo * t.x - hi * t.y;
                    float ohi = hi * t.x + lo * t.y;
                    if (kind == 0) { olo *= 0.125f; ohi *= 0.125f; }
                    myS[sl * 72 + j]      = f2bf(olo);
                    myS[sl * 72 + 32 + j] = f2bf(ohi);
                }
            }
        }
        // readout: 8 lanes x 16B cover one 128B row (wave-private, no barrier)
        const int rl = lane >> 3;             // row sub-index
        const int cl = (lane & 7) * 8;        // col in shorts
        short* dst = (kind == 0 ? Qb : Kb);
#pragma unroll
        for (int p = 0; p < 8; ++p) {
            int rr = p * 8 + rl;
            bf16x8 v = *(const bf16x8*)&myS[rr * 72 + cl];
            *(bf16x8*)(dst + ((size_t)bh * S_ + sbase + rr) * 64 + cl) = v;
        }
    } else {
        // ---- V: scratch [d][s], r=0..3 packed as b64 ----
#pragma unroll
        for (int mi = 0; mi < 4; ++mi)
#pragma unroll
            for (int ni = 0; ni < 4; ++ni) {
                bf16x4 p;
                p[0] = f2bf(acc[mi][ni][0]);
                p[1] = f2bf(acc[mi][ni][1]);
                p[2] = f2bf(acc[mi][ni][2]);
                p[3] = f2bf(acc[mi][ni][3]);
                *(bf16x4*)&myS[(ni * 16 + l16) * 72 + mi * 16 + quad * 4] = p;
            }
        const int rl = lane >> 3;
        const int cl = (lane & 7) * 8;
#pragma unroll
        for (int p = 0; p < 8; ++p) {
            int dd = p * 8 + rl;
            bf16x8 v = *(const bf16x8*)&myS[dd * 72 + cl];
            *(bf16x8*)(Vt + ((size_t)bh * 64 + dd) * S_ + sbase + cl) = v;
        }
    }
}

// ---------------------------------------------------------------------------
// MFMA flash attention R13: Bq=128 (4 waves x 32 q-rows), LDS-staged K/V
// with XOR-swizzled staging (T2 via pre-swizzled GLOBAL source, LDS linear),
// counted-vmcnt double-buffer (2 raw s_barriers/tile, vmcnt(4), never a
// full lgkm drain), swapped QK^T with packed b64 P-spill (wave-private Ps).
// Per staged tile: 4 gload16/wave; K/V frag ds_read_b128 conflict-free
// (2-way). Shifted-exp softmax p=exp(s-8); l row-sums via ones-MFMA.
// Split-K task map (Bq=128, Bk=64): 40 tasks/bh; qb 0-3 ->1 chunk,
// 4-7 ->2, 8-11 ->3, 12-15 ->4. Grid 1280 = 8 XCD x 4 bh x 40 tasks.
// LDS: Ks/Vs dbuf 32KB + Ps[128][72] 18KB = 50KB -> 3 blocks/CU.
// ---------------------------------------------------------------------------
__global__ __launch_bounds__(256, 3) void attn_kernel(
    const short* __restrict__ Qb, const short* __restrict__ Kb,
    const short* __restrict__ Vt, short* __restrict__ Opart,
    float* __restrict__ lpart)
{
    __shared__ short Ks[2][64 * 64];
    __shared__ short Vs[2][64 * 64];
    __shared__ short Ps[128][72];

    const int lin = blockIdx.x;          // 0..1279
    const int xcd = lin & 7;
    const int j   = lin >> 3;            // 0..159
    const int bh   = xcd * 4 + (j & 3);
    const int task = j >> 2;             // 0..39

    const int g = task < 4 ? 0 : task < 12 ? 1 : task < 24 ? 2 : 3;
    const int cumstart = g == 0 ? 0 : g == 1 ? 4 : g == 2 ? 12 : 24;
    const int idx = task - cumstart;
    const int qd = idx / (g + 1);
    const int qb = 4 * g + qd;           // 0..15 (128-row q block)
    const int c  = idx - qd * (g + 1);
    const int t0 = c * 8;
    const int t1 = min(2 * qb + 1, c * 8 + 7);

    const int wave = threadIdx.x >> 6, lane = threadIdx.x & 63;
    const int quad = lane >> 4, l16 = lane & 15;
    const int subr  = lane >> 3;         // 0..7 (staging sub-row)
    const int chunk = (lane & 7) ^ subr; // XOR-swizzled 16B chunk index
    const size_t head64 = (size_t)bh * S_ * 64;

    // Q B-frags: 2 chunks of 16 q-rows each (rows qb*128 + wave*32 + m*16)
    bf16x8 qf[2][2];
#pragma unroll
    for (int m = 0; m < 2; ++m) {
        const short* qrow = Qb + head64
            + (size_t)(qb * 128 + wave * 32 + m * 16 + l16) * 64 + quad * 8;
        qf[m][0] = *(const bf16x8*)(qrow);
        qf[m][1] = *(const bf16x8*)(qrow + 32);
    }

    // all-ones bf16 B fragment for l row-sums
    bf16x8 ones;
#pragma unroll
    for (int i = 0; i < 8; ++i) ones[i] = (short)0x3F80;

    // staging: per wave 2 K-issues + 2 V-issues (16 rows each of K d-rows/V)
    // LDS stays LINEAR; swizzle applied on the GLOBAL source chunk so that
    // LDS[row][c] = G[row][c ^ (row&7)] (involution, undone at read).
    auto stage = [&](int buf, int t) {
        const short* kt = Kb + head64 + (size_t)(t * 64 + wave * 16) * 64;
        const short* vt = Vt + head64 + (size_t)(wave * 16) * S_ + t * 64;
        char* kl = (char*)(Ks[buf]) + wave * 2048;
        char* vl = (char*)(Vs[buf]) + wave * 2048;
#pragma unroll
        for (int g2 = 0; g2 < 2; ++g2) {
            gload16(kt + (g2 * 8 + subr) * 64 + chunk * 8, kl + g2 * 1024);
            gload16(vt + (size_t)(g2 * 8 + subr) * S_ + chunk * 8, vl + g2 * 1024);
        }
    };

    f32x4 lacc[2] = {(f32x4)0.f, (f32x4)0.f};
    f32x4 oacc[2][4];
#pragma unroll
    for (int m = 0; m < 2; ++m)
#pragma unroll
        for (int nt = 0; nt < 4; ++nt) oacc[m][nt] = (f32x4)0.f;

    stage(0, t0);
    int buf = 0;
    for (int t = t0; t <= t1; ++t) {
        __builtin_amdgcn_s_barrier();        // readers of buf^1 (t-1) done
        if (t < t1) stage(buf ^ 1, t + 1);   // prefetch next tile
        if (t < t1) { asm volatile("s_waitcnt vmcnt(4)" ::: "memory"); }
        else        { asm volatile("s_waitcnt vmcnt(0)" ::: "memory"); }
        __builtin_amdgcn_s_barrier();        // all waves' tile-t data in LDS
        __builtin_amdgcn_sched_barrier(0);

        const short* kbuf = Ks[buf];
        const short* vbuf = Vs[buf];

        // ---- QK^T (swapped): s4[m][nt]: row k = quad*4+r, col q = l16 ----
        f32x4 s4[2][4];
#pragma unroll
        for (int nt = 0; nt < 4; ++nt) {
            const int krow = nt * 16 + l16;
            const int sw = krow & 7;
            bf16x8 k0 = *(const bf16x8*)(kbuf + krow * 64 + ((quad ^ sw) << 3));
            bf16x8 k1 = *(const bf16x8*)(kbuf + krow * 64 + (((quad + 4) ^ sw) << 3));
#pragma unroll
            for (int m = 0; m < 2; ++m) {
                f32x4 a = (f32x4)0.f;
                a = __builtin_amdgcn_mfma_f32_16x16x32_bf16(k0, qf[m][0], a, 0, 0, 0);
                a = __builtin_amdgcn_mfma_f32_16x16x32_bf16(k1, qf[m][1], a, 0, 0, 0);
                s4[m][nt] = a;
            }
        }

        // causal mask: only the two boundary tiles can mask
        if (t >= 2 * qb) {
            const int kbase = (t - 2 * qb) * 64;
#pragma unroll
            for (int m = 0; m < 2; ++m) {
                const int qq = wave * 32 + m * 16 + l16;
#pragma unroll
                for (int nt = 0; nt < 4; ++nt)
#pragma unroll
                    for (int r = 0; r < 4; ++r)
                        if (kbase + nt * 16 + quad * 4 + r > qq)
                            s4[m][nt][r] = -INFINITY;
            }
        }

        // ---- p = exp(s-8) -> packed b64 P-spill (k-contig per lane) ----
#pragma unroll
        for (int m = 0; m < 2; ++m)
#pragma unroll
            for (int nt = 0; nt < 4; ++nt) {
                bf16x4 p;
#pragma unroll
                for (int r = 0; r < 4; ++r)
                    p[r] = f2bf(__expf(s4[m][nt][r] - 8.0f));  // masked -> 0
                *(bf16x4*)&Ps[wave * 32 + m * 16 + l16][nt * 16 + quad * 4] = p;
            }

        // ---- read P A-frags (row q = l16, k-contig); wave-private rows ----
        bf16x8 pa[2][2];
#pragma unroll
        for (int m = 0; m < 2; ++m) {
            pa[m][0] = *(const bf16x8*)&Ps[wave * 32 + m * 16 + l16][quad * 8];
            pa[m][1] = *(const bf16x8*)&Ps[wave * 32 + m * 16 + l16][32 + quad * 8];
        }

        // ---- l row-sum (MFMA with ones) ----
#pragma unroll
        for (int m = 0; m < 2; ++m) {
            lacc[m] = __builtin_amdgcn_mfma_f32_16x16x32_bf16(pa[m][0], ones, lacc[m], 0, 0, 0);
            lacc[m] = __builtin_amdgcn_mfma_f32_16x16x32_bf16(pa[m][1], ones, lacc[m], 0, 0, 0);
        }

        // ---- PV: V B-frags from LDS (swizzle-undone), 2 chunks share ----
#pragma unroll
        for (int nt = 0; nt < 4; ++nt) {
            const int vrow = nt * 16 + l16;
            const int sw = vrow & 7;
            bf16x8 v0 = *(const bf16x8*)(vbuf + vrow * 64 + ((quad ^ sw) << 3));
            bf16x8 v1 = *(const bf16x8*)(vbuf + vrow * 64 + (((quad + 4) ^ sw) << 3));
#pragma unroll
            for (int m = 0; m < 2; ++m) {
                oacc[m][nt] = __builtin_amdgcn_mfma_f32_16x16x32_bf16(
                    pa[m][0], v0, oacc[m][nt], 0, 0, 0);
                oacc[m][nt] = __builtin_amdgcn_mfma_f32_16x16x32_bf16(
                    pa[m][1], v1, oacc[m][nt], 0, 0, 0);
            }
        }
        buf ^= 1;
    }

    // ---- epilogue: unnormalized partial O (bf16) + l (f32) ----
    const int pidx = bh * 40 + task;
#pragma unroll
    for (int m = 0; m < 2; ++m)
#pragma unroll
        for (int r = 0; r < 4; ++r) {
            int ql = wave * 32 + m * 16 + quad * 4 + r;
            short* orow = Opart + (size_t)pidx * 8192 + ql * 64;
#pragma unroll
            for (int nt = 0; nt < 4; ++nt)
                orow[nt * 16 + l16] = f2bf(oacc[m][nt][r]);
            if (l16 == 0)
                lpart[(size_t)pidx * 128 + ql] = lacc[m][r];
        }
}

// ---------------------------------------------------------------------------
// Combine split-K partials: attnb = (sum_c O_c) / (sum_c l_c)
// grid (16 qb, 32 bh), 256 thr: thread = (q = tid>>1, 32-d half).
// ---------------------------------------------------------------------------
__global__ __launch_bounds__(256) void combine_kernel(
    const short* __restrict__ Opart, const float* __restrict__ lpart,
    short* __restrict__ attnb)
{
    const int qb = blockIdx.x, bh = blockIdx.y;
    const int g = qb >> 2, nch = g + 1;
    const int cumstart = g == 0 ? 0 : g == 1 ? 4 : g == 2 ? 12 : 24;
    const int cbase = bh * 40 + cumstart + (qb - 4 * g) * nch;
    const int q = threadIdx.x >> 1;
    const int dg = (threadIdx.x & 1) * 32;

    float lsum = 0.f;
    float acc[32];
#pragma unroll
    for (int i = 0; i < 32; ++i) acc[i] = 0.f;

    for (int cc = 0; cc < nch; ++cc) {
        lsum += lpart[(size_t)(cbase + cc) * 128 + q];
        const short* src = Opart + (size_t)(cbase + cc) * 8192 + q * 64 + dg;
#pragma unroll
        for (int w = 0; w < 4; ++w) {
            bf16x8 o = *(const bf16x8*)(src + w * 8);
#pragma unroll
            for (int i = 0; i < 8; ++i) acc[w * 8 + i] += bf2f(o[i]);
        }
    }
    float inv = 1.0f / lsum;
    const int b = bh >> 4, h = bh & 15;
    short* dst = attnb + (size_t)(b * S_ + qb * 128 + q) * 1024 + h * 64 + dg;
#pragma unroll
    for (int w = 0; w < 4; ++w) {
        bf16x8 r;
#pragma unroll
        for (int i = 0; i < 8; ++i) r[i] = f2bf(acc[w * 8 + i] * inv);
        *(bf16x8*)(dst + w * 8) = r;
    }
}

// ---------------------------------------------------------------------------
extern "C" void kernel_launch(void* const* d_in, const int* in_sizes, int n_in,
                              void* d_out, int out_size, void* d_ws, size_t ws_size,
                              hipStream_t stream)
{
    const float* x     = (const float*)d_in[0];   // [2,2048,1024]
    const float* w_qkv = (const float*)d_in[1];   // [1024,3072]
    const float* w_out = (const float*)d_in[2];   // [1024,1024]
    float* out = (float*)d_out;                   // [2,2048,1024]

    // workspace layout (bf16 shorts unless noted), ~64 MB total
    short* Qb   = (short*)d_ws;                        // [32][2048][64] 8.4 MB
    short* Kb   = Qb   + (size_t)4096 * 1024;          // [32][2048][64] 8.4 MB
    short* Vt   = Kb   + (size_t)4096 * 1024;          // [32][64][2048] 8.4 MB
    short* Xb   = Vt   + (size_t)4096 * 1024;          // [4096][1024]   8.4 MB
    short* Wqt  = Xb   + (size_t)4096 * 1024;          // [3072][1024]   6.3 MB
    short* Wot  = Wqt  + (size_t)3072 * 1024;          // [1024][1024]   2.1 MB
    float2* tab = (float2*)(Wot + (size_t)1024 * 1024); // [2048*32]     0.5 MB
    short* Opart = (short*)(tab + 2048 * 32);          // 1280*8192     21.0 MB
    float* lbuf  = (float*)(Opart + (size_t)1280 * 8192); // 1280*128    0.65 MB
    short* attnb = Xb;   // Xb dead after gemm_qkv; reuse for attention output

    // 1) conversions / transposes / RoPE table
    cvt_bf16_kernel<<<(4096 * 1024 / 8) / 256, 256, 0, stream>>>(x, Xb);
    transpose_cvt_kernel<<<dim3(3072 / 64, 1024 / 64), 256, 0, stream>>>(
        w_qkv, Wqt, 1024, 3072);
    transpose_cvt_kernel<<<dim3(1024 / 64, 1024 / 64), 256, 0, stream>>>(
        w_out, Wot, 1024, 1024);
    rope_tab_kernel<<<(2048 * 32) / 256, 256, 0, stream>>>(tab);

    // 2) fused QKV GEMM (ring-3 pipelined K-loop): Xb @ Wqt^T -> Qb/Kb/Vt
    gemm_qkv<<<dim3(3072 / 128, 4096 / 128), 256, 49152, stream>>>(
        Xb, Wqt, tab, Qb, Kb, Vt);

    // 3) split-K flash attention (Bq=128, XCD-swizzled) -> partials
    attn_kernel<<<1280, 256, 0, stream>>>(Qb, Kb, Vt, Opart, lbuf);

    // 4) combine partials -> attnb bf16 [4096][1024]
    combine_kernel<<<dim3(16, 32), 256, 0, stream>>>(Opart, lbuf, attnb);

    // 5) out = attnb @ Wot^T  (fp32 out, ring-3 pipelined, 512 blocks)
    gemm_bt_f32<<<dim3(1024 / 64, 4096 / 128), 256, 0, stream>>>(
        attnb, Wot, out, 4096, 1024, 1024);
}

// Round 4
// 172.417 us; speedup vs baseline: 1.2548x; 1.0353x over previous
//
#include <hip/hip_runtime.h>
#include <math.h>
#include <type_traits>

// Problem constants (B=2, S=2048, D=1024, H=16, hd=64)
#define B_  2
#define S_  2048
#define D_  1024
#define H_  16

typedef short bf16x8 __attribute__((ext_vector_type(8)));
typedef short bf16x4 __attribute__((ext_vector_type(4)));
typedef float f32x4  __attribute__((ext_vector_type(4)));

// fp32 -> bf16 bits, round-to-nearest-even (finite inputs only)
__device__ __forceinline__ short f2bf(float f) {
    unsigned u = __builtin_bit_cast(unsigned, f);
    u += 0x7FFFu + ((u >> 16) & 1u);
    return (short)(u >> 16);
}
__device__ __forceinline__ float bf2f(short s) {
    unsigned u = ((unsigned)(unsigned short)s) << 16;
    return __builtin_bit_cast(float, u);
}

// async global->LDS, 16B per lane; LDS dest = wave-uniform base + lane*16
__device__ __forceinline__ void gload16(const short* g, const void* l) {
    __builtin_amdgcn_global_load_lds(
        (const __attribute__((address_space(1))) void*)g,
        (__attribute__((address_space(3))) void*)l, 16, 0, 0);
}

// ---------------------------------------------------------------------------
// Merged prologue kernel (R14: was 4 launches -> 1).
// blocks [0,2048): fp32->bf16 cvt of x (8 elems/thread)
// blocks [2048,2816): w_qkv [1024][3072] -> Wqt [3072][1024] transpose+cvt
// blocks [2816,3072): w_out [1024][1024] -> Wot [1024][1024] transpose+cvt
// blocks [3072,3328): RoPE cos/sin table
// ---------------------------------------------------------------------------
__device__ __forceinline__ void transpose_body(
    const float* __restrict__ in, short* __restrict__ out, int K, int N,
    int bx, int by, short (*t)[72], int tid)
{
    const int k0 = by * 64, n0 = bx * 64;
    const int r = tid >> 2;
    const int c = (tid & 3) * 16;
    const float* src = in + (size_t)(k0 + r) * N + n0 + c;
#pragma unroll
    for (int i = 0; i < 16; ++i) t[c + i][r] = f2bf(src[i]);
    __syncthreads();
    short* dst = out + (size_t)(n0 + r) * K + k0 + c;
    *(bf16x8*)(dst)     = *(const bf16x8*)&t[r][c];
    *(bf16x8*)(dst + 8) = *(const bf16x8*)&t[r][c + 8];
}

__global__ __launch_bounds__(256) void prep_kernel(
    const float* __restrict__ x, short* __restrict__ Xb,
    const float* __restrict__ w_qkv, short* __restrict__ Wqt,
    const float* __restrict__ w_out, short* __restrict__ Wot,
    float2* __restrict__ tab)
{
    __shared__ short t[64][72];
    const int bid = blockIdx.x;
    const int tid = threadIdx.x;
    if (bid < 2048) {
        int i = (bid * 256 + tid) * 8;
        float4 a = *(const float4*)(x + i);
        float4 b = *(const float4*)(x + i + 4);
        bf16x8 o;
        o[0] = f2bf(a.x); o[1] = f2bf(a.y); o[2] = f2bf(a.z); o[3] = f2bf(a.w);
        o[4] = f2bf(b.x); o[5] = f2bf(b.y); o[6] = f2bf(b.z); o[7] = f2bf(b.w);
        *(bf16x8*)(Xb + i) = o;
    } else if (bid < 2816) {
        int b2 = bid - 2048;                       // 48 x 16
        transpose_body(w_qkv, Wqt, 1024, 3072, b2 % 48, b2 / 48, t, tid);
    } else if (bid < 3072) {
        int b2 = bid - 2816;                       // 16 x 16
        transpose_body(w_out, Wot, 1024, 1024, b2 % 16, b2 / 16, t, tid);
    } else {
        int idx = (bid - 3072) * 256 + tid;        // < 2048*32
        int j = idx & 31, s = idx >> 5;
        float inv = powf(10000.0f, -(float)j * (1.0f / 32.0f));
        float sn, cs;
        sincosf((float)s * inv, &sn, &cs);
        tab[idx] = make_float2(cs, sn);
    }
}

// ---------------------------------------------------------------------------
// bf16 MFMA GEMM, 128x64 tile (M x N), BK=32, fp32 out. 256 thr = 4 waves
// (2x2). Triple-buffered LDS ring, prefetch distance 2, counted vmcnt(3),
// one raw s_barrier per K-step.
// R14: 1-D grid + bijective XCD-chunked swizzle (each XCD owns 4 complete
// row-panels x all col-blocks -> A panels fetched once per owning XCD).
// ---------------------------------------------------------------------------
__global__ __launch_bounds__(256) void gemm_bt_f32(
    const short* __restrict__ A, const short* __restrict__ Bt,
    float* __restrict__ C, int M, int N, int K)
{
    __shared__ short smem[18432];   // 3 x (As 8KB | Bs 4KB) = 36864 B

    const int tid  = threadIdx.x;
    const int wave = tid >> 6, lane = tid & 63;
    const int quad = lane >> 4, l16 = lane & 15;
    const int wm = wave >> 1, wn = wave & 1;

    const int nbx = N >> 6;                       // col-blocks
    const int cpx = gridDim.x >> 3;               // blocks per XCD chunk
    const int lin = blockIdx.x;
    const int swz = (lin & 7) * cpx + (lin >> 3); // bijective (grid % 8 == 0)
    const int row0 = (swz / nbx) * 128, col0 = (swz % nbx) * 64;

    f32x4 acc[4][2];
#pragma unroll
    for (int mi = 0; mi < 4; ++mi)
#pragma unroll
        for (int ni = 0; ni < 2; ++ni) acc[mi][ni] = (f32x4)0.f;

    const int sr = tid >> 2;
    const int sc = (tid & 3) * 8;
    const short* a0 = A  + (size_t)(row0 + sr) * K + sc;
    const short* a1 = A  + (size_t)(row0 + 64 + sr) * K + sc;
    const short* b0 = Bt + (size_t)(col0 + sr) * K + sc;

    auto stage = [&](int b, int kt) {
        char* l = (char*)(smem + b * 6144) + wave * 1024;
        const int k0 = kt * 32;
        gload16(a0 + k0, l);            // A rows 0-63
        gload16(a1 + k0, l + 4096);     // A rows 64-127
        gload16(b0 + k0, l + 8192);     // B rows 0-63
    };

    const int NT = K >> 5;              // 32
    stage(0, 0);
    stage(1, 1);
    int bufid = 0;
    for (int kt = 0; kt < NT; ++kt) {
        if (kt + 1 < NT) { asm volatile("s_waitcnt vmcnt(3)" ::: "memory"); }
        else             { asm volatile("s_waitcnt vmcnt(0)" ::: "memory"); }
        __builtin_amdgcn_s_barrier();
        __builtin_amdgcn_sched_barrier(0);
        if (kt + 2 < NT) {
            int nb = bufid + 2; if (nb >= 3) nb -= 3;
            stage(nb, kt + 2);          // issue-early: 2 steps ahead
        }

        const short* As = smem + bufid * 6144;
        const short* Bs = As + 4096;
        bf16x8 af[4], bfr[2];
#pragma unroll
        for (int mi = 0; mi < 4; ++mi)
            af[mi] = *(const bf16x8*)(As + (wm * 64 + mi * 16 + l16) * 32 + quad * 8);
#pragma unroll
        for (int ni = 0; ni < 2; ++ni)
            bfr[ni] = *(const bf16x8*)(Bs + (wn * 32 + ni * 16 + l16) * 32 + quad * 8);
#pragma unroll
        for (int mi = 0; mi < 4; ++mi)
#pragma unroll
            for (int ni = 0; ni < 2; ++ni)
                acc[mi][ni] = __builtin_amdgcn_mfma_f32_16x16x32_bf16(
                    af[mi], bfr[ni], acc[mi][ni], 0, 0, 0);

        bufid = (bufid + 1 == 3) ? 0 : bufid + 1;
    }

#pragma unroll
    for (int mi = 0; mi < 4; ++mi)
#pragma unroll
        for (int ni = 0; ni < 2; ++ni)
#pragma unroll
            for (int r = 0; r < 4; ++r) {
                int row = row0 + wm * 64 + mi * 16 + quad * 4 + r;
                int col = col0 + wn * 32 + ni * 16 + l16;
                C[(size_t)row * N + col] = acc[mi][ni][r];
            }
}

// ---------------------------------------------------------------------------
// Fused QKV GEMM (128x128, BK=32) with RoPE + head-major repack + V
// transpose in an LDS-STAGED epilogue. Ring-3 K-loop (3 x 16KB), prefetch
// distance 2, counted vmcnt(4), one raw s_barrier per step. Dynamic LDS
// 49152 B (3 blocks/CU). Kb unpadded stride-64.
// R14: 1-D grid 768 + bijective XCD-chunked swizzle (96 blocks/XCD = 4 full
// row-panels x 24 cols): A panels hit the owning XCD's L2 once, cutting the
// 3x FETCH over-read seen in R0 counters (43.5 MB vs 14.7 ideal).
// ---------------------------------------------------------------------------
__global__ __launch_bounds__(256) void gemm_qkv(
    const short* __restrict__ A, const short* __restrict__ Bt,
    const float2* __restrict__ tab,
    short* __restrict__ Qb, short* __restrict__ Kb, short* __restrict__ Vt)
{
    const int K = 1024;
    extern __shared__ short smem[];          // 49152 B = 3 x (As 8KB | Bs 8KB)
    short* Sc = smem;                        // epilogue: 4 x (64*72)

    const int tid  = threadIdx.x;
    const int wave = tid >> 6, lane = tid & 63;
    const int quad = lane >> 4, l16 = lane & 15;
    const int wm = wave >> 1, wn = wave & 1;

    const int lin = blockIdx.x;                   // 0..767
    const int swz = (lin & 7) * 96 + (lin >> 3);  // bijective
    const int row0 = (swz / 24) * 128, col0 = (swz % 24) * 128;

    f32x4 acc[4][4];
#pragma unroll
    for (int mi = 0; mi < 4; ++mi)
#pragma unroll
        for (int ni = 0; ni < 4; ++ni) acc[mi][ni] = (f32x4)0.f;

    const int sr = tid >> 2;
    const int sc = (tid & 3) * 8;
    const short* a0 = A  + (size_t)(row0 + sr) * K + sc;
    const short* a1 = A  + (size_t)(row0 + 64 + sr) * K + sc;
    const short* b0 = Bt + (size_t)(col0 + sr) * K + sc;
    const short* b1 = Bt + (size_t)(col0 + 64 + sr) * K + sc;

    auto stage = [&](int b, int kt) {
        char* l = (char*)(smem + b * 8192) + wave * 1024;
        const int k0 = kt * 32;
        gload16(a0 + k0, l);            // A rows 0-63
        gload16(a1 + k0, l + 4096);     // A rows 64-127
        gload16(b0 + k0, l + 8192);     // B rows 0-63
        gload16(b1 + k0, l + 12288);    // B rows 64-127
    };

    const int NT = K >> 5;              // 32
    stage(0, 0);
    stage(1, 1);
    int bufid = 0;
    for (int kt = 0; kt < NT; ++kt) {
        if (kt + 1 < NT) { asm volatile("s_waitcnt vmcnt(4)" ::: "memory"); }
        else             { asm volatile("s_waitcnt vmcnt(0)" ::: "memory"); }
        __builtin_amdgcn_s_barrier();       // all waves' tile-kt data visible
        __builtin_amdgcn_sched_barrier(0);  // pin ds_reads/stage below barrier
        if (kt + 2 < NT) {
            int nb = bufid + 2; if (nb >= 3) nb -= 3;
            stage(nb, kt + 2);
        }

        const short* As = smem + bufid * 8192;
        const short* Bs = As + 4096;
        bf16x8 af[4], bfr[4];
#pragma unroll
        for (int mi = 0; mi < 4; ++mi)
            af[mi] = *(const bf16x8*)(As + (wm * 64 + mi * 16 + l16) * 32 + quad * 8);
#pragma unroll
        for (int ni = 0; ni < 4; ++ni)
            bfr[ni] = *(const bf16x8*)(Bs + (wn * 64 + ni * 16 + l16) * 32 + quad * 8);
#pragma unroll
        for (int mi = 0; mi < 4; ++mi)
#pragma unroll
            for (int ni = 0; ni < 4; ++ni)
                acc[mi][ni] = __builtin_amdgcn_mfma_f32_16x16x32_bf16(
                    af[mi], bfr[ni], acc[mi][ni], 0, 0, 0);

        bufid = (bufid + 1 == 3) ? 0 : bufid + 1;
    }

    __syncthreads();   // full drain; Sc may now overwrite the ring buffers

    const int sec  = (col0 + wn * 64) >> 6;   // 0..47
    const int h    = sec & 15;
    const int kind = sec >> 4;                // 0=Q, 1=K, 2=V
    short* myS = Sc + wave * 4608;            // 64 x 72 scratch

    const int mrow0 = row0 + wm * 64;         // block never straddles b
    const int b  = mrow0 >> 11;
    const int bh = b * 16 + h;
    const int sbase = mrow0 & (S_ - 1);

    if (kind < 2) {
        // ---- Q/K: RoPE -> scratch [s][d] ----
#pragma unroll
        for (int mi = 0; mi < 4; ++mi) {
#pragma unroll
            for (int r = 0; r < 4; ++r) {
                int sl = mi * 16 + quad * 4 + r;
                int s = sbase + sl;
#pragma unroll
                for (int ni = 0; ni < 2; ++ni) {
                    int j = ni * 16 + l16;
                    float2 t = tab[s * 32 + j];
                    float lo = acc[mi][ni][r], hi = acc[mi][ni + 2][r];
                    float olo = lo * t.x - hi * t.y;
                    float ohi = hi * t.x + lo * t.y;
                    if (kind == 0) { olo *= 0.125f; ohi *= 0.125f; }
                    myS[sl * 72 + j]      = f2bf(olo);
                    myS[sl * 72 + 32 + j] = f2bf(ohi);
                }
            }
        }
        // readout: 8 lanes x 16B cover one 128B row (wave-private, no barrier)
        const int rl = lane >> 3;             // row sub-index
        const int cl = (lane & 7) * 8;        // col in shorts
        short* dst = (kind == 0 ? Qb : Kb);
#pragma unroll
        for (int p = 0; p < 8; ++p) {
            int rr = p * 8 + rl;
            bf16x8 v = *(const bf16x8*)&myS[rr * 72 + cl];
            *(bf16x8*)(dst + ((size_t)bh * S_ + sbase + rr) * 64 + cl) = v;
        }
    } else {
        // ---- V: scratch [d][s], r=0..3 packed as b64 ----
#pragma unroll
        for (int mi = 0; mi < 4; ++mi)
#pragma unroll
            for (int ni = 0; ni < 4; ++ni) {
                bf16x4 p;
                p[0] = f2bf(acc[mi][ni][0]);
                p[1] = f2bf(acc[mi][ni][1]);
                p[2] = f2bf(acc[mi][ni][2]);
                p[3] = f2bf(acc[mi][ni][3]);
                *(bf16x4*)&myS[(ni * 16 + l16) * 72 + mi * 16 + quad * 4] = p;
            }
        const int rl = lane >> 3;
        const int cl = (lane & 7) * 8;
#pragma unroll
        for (int p = 0; p < 8; ++p) {
            int dd = p * 8 + rl;
            bf16x8 v = *(const bf16x8*)&myS[dd * 72 + cl];
            *(bf16x8*)(Vt + ((size_t)bh * 64 + dd) * S_ + sbase + cl) = v;
        }
    }
}

// ---------------------------------------------------------------------------
// MFMA flash attention: Bq=128 (4 waves x 32 q-rows), LDS-staged K/V with
// XOR-swizzled staging (pre-swizzled GLOBAL source, LDS linear), counted-
// vmcnt double-buffer, swapped QK^T with packed b64 P-spill (wave-private).
// R14: s_setprio(1) around the QK^T and PV MFMA clusters — blocks on a CU
// are independent split-K tasks at different phases (the m191 regime where
// setprio pays, unlike lockstep GEMM).
// Split-K task map (Bq=128, Bk=64): 40 tasks/bh. Grid 1280, XCD-swizzled.
// LDS: Ks/Vs dbuf 32KB + Ps[128][72] 18KB = 50KB -> 3 blocks/CU.
// ---------------------------------------------------------------------------
__global__ __launch_bounds__(256, 3) void attn_kernel(
    const short* __restrict__ Qb, const short* __restrict__ Kb,
    const short* __restrict__ Vt, short* __restrict__ Opart,
    float* __restrict__ lpart)
{
    __shared__ short Ks[2][64 * 64];
    __shared__ short Vs[2][64 * 64];
    __shared__ short Ps[128][72];

    const int lin = blockIdx.x;          // 0..1279
    const int xcd = lin & 7;
    const int j   = lin >> 3;            // 0..159
    const int bh   = xcd * 4 + (j & 3);
    const int task = j >> 2;             // 0..39

    const int g = task < 4 ? 0 : task < 12 ? 1 : task < 24 ? 2 : 3;
    const int cumstart = g == 0 ? 0 : g == 1 ? 4 : g == 2 ? 12 : 24;
    const int idx = task - cumstart;
    const int qd = idx / (g + 1);
    const int qb = 4 * g + qd;           // 0..15 (128-row q block)
    const int c  = idx - qd * (g + 1);
    const int t0 = c * 8;
    const int t1 = min(2 * qb + 1, c * 8 + 7);

    const int wave = threadIdx.x >> 6, lane = threadIdx.x & 63;
    const int quad = lane >> 4, l16 = lane & 15;
    const int subr  = lane >> 3;         // 0..7 (staging sub-row)
    const int chunk = (lane & 7) ^ subr; // XOR-swizzled 16B chunk index
    const size_t head64 = (size_t)bh * S_ * 64;

    // Q B-frags: 2 chunks of 16 q-rows each (rows qb*128 + wave*32 + m*16)
    bf16x8 qf[2][2];
#pragma unroll
    for (int m = 0; m < 2; ++m) {
        const short* qrow = Qb + head64
            + (size_t)(qb * 128 + wave * 32 + m * 16 + l16) * 64 + quad * 8;
        qf[m][0] = *(const bf16x8*)(qrow);
        qf[m][1] = *(const bf16x8*)(qrow + 32);
    }

    // all-ones bf16 B fragment for l row-sums
    bf16x8 ones;
#pragma unroll
    for (int i = 0; i < 8; ++i) ones[i] = (short)0x3F80;

    // staging: LDS LINEAR; swizzle applied on the GLOBAL source chunk so
    // LDS[row][c] = G[row][c ^ (row&7)] (involution, undone at read).
    auto stage = [&](int buf, int t) {
        const short* kt = Kb + head64 + (size_t)(t * 64 + wave * 16) * 64;
        const short* vt = Vt + head64 + (size_t)(wave * 16) * S_ + t * 64;
        char* kl = (char*)(Ks[buf]) + wave * 2048;
        char* vl = (char*)(Vs[buf]) + wave * 2048;
#pragma unroll
        for (int g2 = 0; g2 < 2; ++g2) {
            gload16(kt + (g2 * 8 + subr) * 64 + chunk * 8, kl + g2 * 1024);
            gload16(vt + (size_t)(g2 * 8 + subr) * S_ + chunk * 8, vl + g2 * 1024);
        }
    };

    f32x4 lacc[2] = {(f32x4)0.f, (f32x4)0.f};
    f32x4 oacc[2][4];
#pragma unroll
    for (int m = 0; m < 2; ++m)
#pragma unroll
        for (int nt = 0; nt < 4; ++nt) oacc[m][nt] = (f32x4)0.f;

    stage(0, t0);
    int buf = 0;
    for (int t = t0; t <= t1; ++t) {
        __builtin_amdgcn_s_barrier();        // readers of buf^1 (t-1) done
        if (t < t1) stage(buf ^ 1, t + 1);   // prefetch next tile
        if (t < t1) { asm volatile("s_waitcnt vmcnt(4)" ::: "memory"); }
        else        { asm volatile("s_waitcnt vmcnt(0)" ::: "memory"); }
        __builtin_amdgcn_s_barrier();        // all waves' tile-t data in LDS
        __builtin_amdgcn_sched_barrier(0);

        const short* kbuf = Ks[buf];
        const short* vbuf = Vs[buf];

        // ---- QK^T (swapped): s4[m][nt]: row k = quad*4+r, col q = l16 ----
        f32x4 s4[2][4];
        __builtin_amdgcn_s_setprio(1);
#pragma unroll
        for (int nt = 0; nt < 4; ++nt) {
            const int krow = nt * 16 + l16;
            const int sw = krow & 7;
            bf16x8 k0 = *(const bf16x8*)(kbuf + krow * 64 + ((quad ^ sw) << 3));
            bf16x8 k1 = *(const bf16x8*)(kbuf + krow * 64 + (((quad + 4) ^ sw) << 3));
#pragma unroll
            for (int m = 0; m < 2; ++m) {
                f32x4 a = (f32x4)0.f;
                a = __builtin_amdgcn_mfma_f32_16x16x32_bf16(k0, qf[m][0], a, 0, 0, 0);
                a = __builtin_amdgcn_mfma_f32_16x16x32_bf16(k1, qf[m][1], a, 0, 0, 0);
                s4[m][nt] = a;
            }
        }
        __builtin_amdgcn_s_setprio(0);

        // causal mask: only the two boundary tiles can mask
        if (t >= 2 * qb) {
            const int kbase = (t - 2 * qb) * 64;
#pragma unroll
            for (int m = 0; m < 2; ++m) {
                const int qq = wave * 32 + m * 16 + l16;
#pragma unroll
                for (int nt = 0; nt < 4; ++nt)
#pragma unroll
                    for (int r = 0; r < 4; ++r)
                        if (kbase + nt * 16 + quad * 4 + r > qq)
                            s4[m][nt][r] = -INFINITY;
            }
        }

        // ---- p = exp(s-8) -> packed b64 P-spill (k-contig per lane) ----
#pragma unroll
        for (int m = 0; m < 2; ++m)
#pragma unroll
            for (int nt = 0; nt < 4; ++nt) {
                bf16x4 p;
#pragma unroll
                for (int r = 0; r < 4; ++r)
                    p[r] = f2bf(__expf(s4[m][nt][r] - 8.0f));  // masked -> 0
                *(bf16x4*)&Ps[wave * 32 + m * 16 + l16][nt * 16 + quad * 4] = p;
            }

        // ---- read P A-frags (row q = l16, k-contig); wave-private rows ----
        bf16x8 pa[2][2];
#pragma unroll
        for (int m = 0; m < 2; ++m) {
            pa[m][0] = *(const bf16x8*)&Ps[wave * 32 + m * 16 + l16][quad * 8];
            pa[m][1] = *(const bf16x8*)&Ps[wave * 32 + m * 16 + l16][32 + quad * 8];
        }

        // ---- l row-sum + PV (MFMA cluster, prio-boosted) ----
        __builtin_amdgcn_s_setprio(1);
#pragma unroll
        for (int m = 0; m < 2; ++m) {
            lacc[m] = __builtin_amdgcn_mfma_f32_16x16x32_bf16(pa[m][0], ones, lacc[m], 0, 0, 0);
            lacc[m] = __builtin_amdgcn_mfma_f32_16x16x32_bf16(pa[m][1], ones, lacc[m], 0, 0, 0);
        }
#pragma unroll
        for (int nt = 0; nt < 4; ++nt) {
            const int vrow = nt * 16 + l16;
            const int sw = vrow & 7;
            bf16x8 v0 = *(const bf16x8*)(vbuf + vrow * 64 + ((quad ^ sw) << 3));
            bf16x8 v1 = *(const bf16x8*)(vbuf + vrow * 64 + (((quad + 4) ^ sw) << 3));
#pragma unroll
            for (int m = 0; m < 2; ++m) {
                oacc[m][nt] = __builtin_amdgcn_mfma_f32_16x16x32_bf16(
                    pa[m][0], v0, oacc[m][nt], 0, 0, 0);
                oacc[m][nt] = __builtin_amdgcn_mfma_f32_16x16x32_bf16(
                    pa[m][1], v1, oacc[m][nt], 0, 0, 0);
            }
        }
        __builtin_amdgcn_s_setprio(0);
        buf ^= 1;
    }

    // ---- epilogue: unnormalized partial O (bf16) + l (f32) ----
    const int pidx = bh * 40 + task;
#pragma unroll
    for (int m = 0; m < 2; ++m)
#pragma unroll
        for (int r = 0; r < 4; ++r) {
            int ql = wave * 32 + m * 16 + quad * 4 + r;
            short* orow = Opart + (size_t)pidx * 8192 + ql * 64;
#pragma unroll
            for (int nt = 0; nt < 4; ++nt)
                orow[nt * 16 + l16] = f2bf(oacc[m][nt][r]);
            if (l16 == 0)
                lpart[(size_t)pidx * 128 + ql] = lacc[m][r];
        }
}

// ---------------------------------------------------------------------------
// Combine split-K partials: attnb = (sum_c O_c) / (sum_c l_c)
// grid (16 qb, 32 bh), 256 thr: thread = (q = tid>>1, 32-d half).
// ---------------------------------------------------------------------------
__global__ __launch_bounds__(256) void combine_kernel(
    const short* __restrict__ Opart, const float* __restrict__ lpart,
    short* __restrict__ attnb)
{
    const int qb = blockIdx.x, bh = blockIdx.y;
    const int g = qb >> 2, nch = g + 1;
    const int cumstart = g == 0 ? 0 : g == 1 ? 4 : g == 2 ? 12 : 24;
    const int cbase = bh * 40 + cumstart + (qb - 4 * g) * nch;
    const int q = threadIdx.x >> 1;
    const int dg = (threadIdx.x & 1) * 32;

    float lsum = 0.f;
    float acc[32];
#pragma unroll
    for (int i = 0; i < 32; ++i) acc[i] = 0.f;

    for (int cc = 0; cc < nch; ++cc) {
        lsum += lpart[(size_t)(cbase + cc) * 128 + q];
        const short* src = Opart + (size_t)(cbase + cc) * 8192 + q * 64 + dg;
#pragma unroll
        for (int w = 0; w < 4; ++w) {
            bf16x8 o = *(const bf16x8*)(src + w * 8);
#pragma unroll
            for (int i = 0; i < 8; ++i) acc[w * 8 + i] += bf2f(o[i]);
        }
    }
    float inv = 1.0f / lsum;
    const int b = bh >> 4, h = bh & 15;
    short* dst = attnb + (size_t)(b * S_ + qb * 128 + q) * 1024 + h * 64 + dg;
#pragma unroll
    for (int w = 0; w < 4; ++w) {
        bf16x8 r;
#pragma unroll
        for (int i = 0; i < 8; ++i) r[i] = f2bf(acc[w * 8 + i] * inv);
        *(bf16x8*)(dst + w * 8) = r;
    }
}

// ---------------------------------------------------------------------------
extern "C" void kernel_launch(void* const* d_in, const int* in_sizes, int n_in,
                              void* d_out, int out_size, void* d_ws, size_t ws_size,
                              hipStream_t stream)
{
    const float* x     = (const float*)d_in[0];   // [2,2048,1024]
    const float* w_qkv = (const float*)d_in[1];   // [1024,3072]
    const float* w_out = (const float*)d_in[2];   // [1024,1024]
    float* out = (float*)d_out;                   // [2,2048,1024]

    // workspace layout (bf16 shorts unless noted), ~64 MB total
    short* Qb   = (short*)d_ws;                        // [32][2048][64] 8.4 MB
    short* Kb   = Qb   + (size_t)4096 * 1024;          // [32][2048][64] 8.4 MB
    short* Vt   = Kb   + (size_t)4096 * 1024;          // [32][64][2048] 8.4 MB
    short* Xb   = Vt   + (size_t)4096 * 1024;          // [4096][1024]   8.4 MB
    short* Wqt  = Xb   + (size_t)4096 * 1024;          // [3072][1024]   6.3 MB
    short* Wot  = Wqt  + (size_t)3072 * 1024;          // [1024][1024]   2.1 MB
    float2* tab = (float2*)(Wot + (size_t)1024 * 1024); // [2048*32]     0.5 MB
    short* Opart = (short*)(tab + 2048 * 32);          // 1280*8192     21.0 MB
    float* lbuf  = (float*)(Opart + (size_t)1280 * 8192); // 1280*128    0.65 MB
    short* attnb = Xb;   // Xb dead after gemm_qkv; reuse for attention output

    // 1) merged prologue: cvt + both weight transposes + RoPE table
    prep_kernel<<<3328, 256, 0, stream>>>(x, Xb, w_qkv, Wqt, w_out, Wot, tab);

    // 2) fused QKV GEMM (ring-3, XCD-chunked): Xb @ Wqt^T -> Qb/Kb/Vt
    gemm_qkv<<<768, 256, 49152, stream>>>(Xb, Wqt, tab, Qb, Kb, Vt);

    // 3) split-K flash attention (Bq=128, XCD-swizzled) -> partials
    attn_kernel<<<1280, 256, 0, stream>>>(Qb, Kb, Vt, Opart, lbuf);

    // 4) combine partials -> attnb bf16 [4096][1024]
    combine_kernel<<<dim3(16, 32), 256, 0, stream>>>(Opart, lbuf, attnb);

    // 5) out = attnb @ Wot^T  (fp32 out, ring-3, XCD-chunked, 512 blocks)
    gemm_bt_f32<<<512, 256, 0, stream>>>(attnb, Wot, out, 4096, 1024, 1024);
}